// Round 9
// baseline (2098.115 us; speedup 1.0000x reference)
//
#include <hip/hip_runtime.h>

// CrossNetMix fused, MFMA path v2: B=16384, D=1024, L=3, E=4, R=64.
// R7: 512-thread blocks (8 waves) -> 16 waves/CU (was 8): the R5 kernel was
// 85% stall-bound (MfmaUtil 7 + VALU 10 + HBM 13.5, occupancy 22.7%).
// Combine phase now LDS-staged + float4 coalesced. Frag layouts identical
// to verified R5 kernel; convert_frags unchanged.
// mfma_f32_16x16x32_bf16: A[m=l&15][k], B[k][n=l&15], D[m=(l>>4)*4+reg][n=l&15].

typedef __bf16 bf16x8 __attribute__((ext_vector_type(8)));
typedef float f32x4 __attribute__((ext_vector_type(4)));
typedef unsigned short u16;
typedef unsigned int u32;

#define TB   32
#define DIM  1024
#define RR   64
#define NE   4
#define NL   3
#define N1   256

#define VF_PER_LAYER (16*32*2*64*8)   // 524288 u16 per layer (ct,ks,h,lane,i)
#define UF_PER_LAYER (64*8*2*64*8)    // 524288 u16 per layer
#define VF_TOTAL (NL*VF_PER_LAYER)
#define UF_TOTAL (NL*UF_PER_LAYER)

#define MFMA16(a,b,c) __builtin_amdgcn_mfma_f32_16x16x32_bf16(a,b,c,0,0,0)

__device__ __forceinline__ u16 f2bf(float f) {
  u32 u = __float_as_uint(f);
  u32 r = (u + 0x7FFFu + ((u >> 16) & 1u)) >> 16;   // RNE
  return (u16)r;
}
__device__ __forceinline__ float bf2f(u16 b) {
  return __uint_as_float(((u32)b) << 16);
}
__device__ __forceinline__ bf16x8 ld_frag_g(const u16* p) {
  return __builtin_bit_cast(bf16x8, *reinterpret_cast<const uint4*>(p));
}

// ---------- kernel 1: convert V,U fp32 -> fragment-linear bf16 hi/lo ----------
__global__ __launch_bounds__(256)
void convert_frags(const float* __restrict__ Vw, const float* __restrict__ Uw,
                   u16* __restrict__ Vf, u16* __restrict__ Uf) {
  const int id = blockIdx.x * 256 + threadIdx.x;   // 0 .. 196607
  float f[8];
  if (id < NL * 16 * 32 * 64) {            // V path: (l, ct, ks, lane)
    const int lane = id & 63;
    const int ks   = (id >> 6) & 31;
    const int ct   = (id >> 11) & 15;
    const int l    = id >> 15;
    const int col  = ct * 16 + (lane & 15);      // e*64 + r
    const int e = col >> 6, r = col & 63;
    const int kbase = ks * 32 + (lane >> 4) * 8;
    const float* src = Vw + ((size_t)(l * NE + e) * DIM + kbase) * RR + r;
    #pragma unroll
    for (int i = 0; i < 8; ++i) f[i] = src[(size_t)i * RR];
    u16* dst = Vf + (size_t)l * VF_PER_LAYER + ((((size_t)ct * 32 + ks) * 2) * 64 + lane) * 8;
    uint4 hi, lo;
    u16 h[8], lw[8];
    #pragma unroll
    for (int i = 0; i < 8; ++i) { h[i] = f2bf(f[i]); lw[i] = f2bf(f[i] - bf2f(h[i])); }
    hi.x = h[0] | (u32)h[1] << 16;  hi.y = h[2] | (u32)h[3] << 16;
    hi.z = h[4] | (u32)h[5] << 16;  hi.w = h[6] | (u32)h[7] << 16;
    lo.x = lw[0] | (u32)lw[1] << 16; lo.y = lw[2] | (u32)lw[3] << 16;
    lo.z = lw[4] | (u32)lw[5] << 16; lo.w = lw[6] | (u32)lw[7] << 16;
    *reinterpret_cast<uint4*>(dst) = hi;
    *reinterpret_cast<uint4*>(dst + 512) = lo;
  } else {                                  // U path: (l, ct, ks, lane)
    const int u = id - NL * 16 * 32 * 64;
    const int lane = u & 63;
    const int ks   = (u >> 6) & 7;
    const int ct   = (u >> 9) & 63;
    const int l    = u >> 15;
    const int d    = ct * 16 + (lane & 15);
    const int kk   = ks * 32 + (lane >> 4) * 8;  // e*64 + r
    const int e = kk >> 6, rb = kk & 63;
    const float* src = Uw + ((size_t)(l * NE + e) * DIM + d) * RR + rb;
    #pragma unroll
    for (int i = 0; i < 8; ++i) f[i] = src[i];
    u16* dst = Uf + (size_t)l * UF_PER_LAYER + ((((size_t)ct * 8 + ks) * 2) * 64 + lane) * 8;
    uint4 hi, lo;
    u16 h[8], lw[8];
    #pragma unroll
    for (int i = 0; i < 8; ++i) { h[i] = f2bf(f[i]); lw[i] = f2bf(f[i] - bf2f(h[i])); }
    hi.x = h[0] | (u32)h[1] << 16;  hi.y = h[2] | (u32)h[3] << 16;
    hi.z = h[4] | (u32)h[5] << 16;  hi.w = h[6] | (u32)h[7] << 16;
    lo.x = lw[0] | (u32)lw[1] << 16; lo.y = lw[2] | (u32)lw[3] << 16;
    lo.z = lw[4] | (u32)lw[5] << 16; lo.w = lw[6] | (u32)lw[7] << 16;
    *reinterpret_cast<uint4*>(dst) = hi;
    *reinterpret_cast<uint4*>(dst + 512) = lo;
  }
}

// ---------- kernel 2: fused 3-layer CrossNetMix, 8 waves/block ----------
struct SM2 {
  union {
    u16 Ax[2][8][2][64][8];    // GEMM1 A-frags, K-chunk 256 (32KB)
    u16 Wf[2][8][2][64][8];    // GEMM2 A-frags (w), K=256 (32KB)
  } u;
  float vbuf[TB][N1 + 4];      // v after GEMM1; then ubar staging in combine
  float gp4[TB][NE][4];        // gate partial dots (quarters)
  float gate[TB][NE];          // softmaxed gates
};

__global__ __launch_bounds__(512, 4)
void crossnet_mfma(const float* __restrict__ x,
                   const float* __restrict__ Cw,    // (L,E,R,R)
                   const float* __restrict__ bias,  // (L,D)
                   const float* __restrict__ G,     // (E,D)
                   const u16* __restrict__ Vf, const u16* __restrict__ Uf,
                   float* __restrict__ out) {
  __shared__ SM2 sm;
  const int t    = threadIdx.x;     // 0..511
  const int lane = t & 63;
  const int wv   = t >> 6;          // wave 0..7
  const int l15  = lane & 15;
  const int lg   = lane >> 4;       // 0..3
  const int b0   = blockIdx.x * TB;
  const int tc   = t & 31, tr = t >> 5;   // C-step mapping: tr 0..15

  for (int layer = 0; layer < NL; ++layer) {
    const float* xin = (layer == 0) ? x : out;
    const u16* Vfl = Vf + (size_t)layer * VF_PER_LAYER;
    const u16* Ufl = Uf + (size_t)layer * UF_PER_LAYER;
    __syncthreads();   // prev layer's out writes / vbuf IO reads ordered

    // ---- gate pass: gp4[b][e][q] = quarter dot of G[e,:].x_l[b,:] ----
    {
      const int gb = t >> 4;        // 0..31 row
      const int ge = (t >> 2) & 3;  // expert
      const int gq = t & 3;         // quarter
      const float4* xr = reinterpret_cast<const float4*>(xin + (size_t)(b0 + gb) * DIM) + gq * 64;
      const float4* gr = reinterpret_cast<const float4*>(G + (size_t)ge * DIM) + gq * 64;
      float4 sa = {0.f, 0.f, 0.f, 0.f};
      for (int q = 0; q < 64; ++q) {
        float4 a = xr[q], g4 = gr[q];
        sa.x = fmaf(a.x, g4.x, sa.x); sa.y = fmaf(a.y, g4.y, sa.y);
        sa.z = fmaf(a.z, g4.z, sa.z); sa.w = fmaf(a.w, g4.w, sa.w);
      }
      sm.gp4[gb][ge][gq] = (sa.x + sa.y) + (sa.z + sa.w);
    }
    __syncthreads();
    if (t < TB) {                   // softmax over experts for row t
      float z[NE]; float m = -1e30f;
      #pragma unroll
      for (int e = 0; e < NE; ++e) {
        z[e] = (sm.gp4[t][e][0] + sm.gp4[t][e][1]) + (sm.gp4[t][e][2] + sm.gp4[t][e][3]);
        m = fmaxf(m, z[e]);
      }
      float den = 0.f;
      #pragma unroll
      for (int e = 0; e < NE; ++e) { z[e] = expf(z[e] - m); den += z[e]; }
      const float inv = 1.f / den;
      #pragma unroll
      for (int e = 0; e < NE; ++e) sm.gate[t][e] = z[e] * inv;
    }
    // gate[] consumed at Wf-write; ordered by the GEMM1 chunk barriers.

    // ---- GEMM1: v_pre(32x256) = x(32x1024) @ V'(1024x256), bf16x3 MFMA ----
    f32x4 acc[2][2];
    #pragma unroll
    for (int rt = 0; rt < 2; ++rt)
      #pragma unroll
      for (int c = 0; c < 2; ++c) acc[rt][c] = (f32x4){0.f, 0.f, 0.f, 0.f};

    for (int ch = 0; ch < 4; ++ch) {        // K-chunks of 256
      __syncthreads();                       // prior chunk's Ax reads done
      #pragma unroll
      for (int q = 0; q < 4; ++q) {          // stage A chunk -> frag layout
        const int idx = q * 512 + t;         // 0..2047 = r*64 + k4
        const int r = idx >> 6, k4 = idx & 63;
        const float4 v = *reinterpret_cast<const float4*>(
            xin + (size_t)(b0 + r) * DIM + ch * 256 + k4 * 4);
        const int kk = k4 * 4;
        const int ksl = kk >> 5, ii = kk & 7, rt = r >> 4;
        const int lnf = (((kk >> 3) & 3) << 4) | (r & 15);
        u16 h0 = f2bf(v.x), h1 = f2bf(v.y), h2 = f2bf(v.z), h3 = f2bf(v.w);
        u16 e0 = f2bf(v.x - bf2f(h0)), e1 = f2bf(v.y - bf2f(h1));
        u16 e2 = f2bf(v.z - bf2f(h2)), e3 = f2bf(v.w - bf2f(h3));
        uint2 hw, lw;
        hw.x = h0 | (u32)h1 << 16; hw.y = h2 | (u32)h3 << 16;
        lw.x = e0 | (u32)e1 << 16; lw.y = e2 | (u32)e3 << 16;
        *reinterpret_cast<uint2*>(&sm.u.Ax[rt][ksl][0][lnf][ii]) = hw;
        *reinterpret_cast<uint2*>(&sm.u.Ax[rt][ksl][1][lnf][ii]) = lw;
      }
      __syncthreads();
      for (int ks = 0; ks < 8; ++ks) {
        const bf16x8 ah0 = __builtin_bit_cast(bf16x8, *(const uint4*)&sm.u.Ax[0][ks][0][lane][0]);
        const bf16x8 al0 = __builtin_bit_cast(bf16x8, *(const uint4*)&sm.u.Ax[0][ks][1][lane][0]);
        const bf16x8 ah1 = __builtin_bit_cast(bf16x8, *(const uint4*)&sm.u.Ax[1][ks][0][lane][0]);
        const bf16x8 al1 = __builtin_bit_cast(bf16x8, *(const uint4*)&sm.u.Ax[1][ks][1][lane][0]);
        const int kg = ch * 8 + ks;
        #pragma unroll
        for (int c = 0; c < 2; ++c) {
          const int ct = wv * 2 + c;
          const u16* p = Vfl + ((((size_t)ct * 32 + kg) * 2) * 64 + lane) * 8;
          const bf16x8 bh = ld_frag_g(p);
          const bf16x8 bl = ld_frag_g(p + 512);
          acc[0][c] = MFMA16(ah0, bh, acc[0][c]);
          acc[0][c] = MFMA16(ah0, bl, acc[0][c]);
          acc[0][c] = MFMA16(al0, bh, acc[0][c]);
          acc[1][c] = MFMA16(ah1, bh, acc[1][c]);
          acc[1][c] = MFMA16(ah1, bl, acc[1][c]);
          acc[1][c] = MFMA16(al1, bh, acc[1][c]);
        }
      }
    }
    // epilogue: v = tanh(v_pre) -> vbuf[row][col]
    #pragma unroll
    for (int rt = 0; rt < 2; ++rt)
      #pragma unroll
      for (int c = 0; c < 2; ++c)
        #pragma unroll
        for (int reg = 0; reg < 4; ++reg) {
          const int row = rt * 16 + lg * 4 + reg;
          const int col = (wv * 2 + c) * 16 + l15;
          sm.vbuf[row][col] = tanhf(acc[rt][c][reg]);
        }
    __syncthreads();   // vbuf ready; all Ax reads done (Wf union safe below)

    // ---- C-step: rows tr*2+r2, cols g*128+tc*4 (fp32 VALU) ----
    float cacc[2][8];
    #pragma unroll
    for (int r2 = 0; r2 < 2; ++r2)
      #pragma unroll
      for (int j = 0; j < 8; ++j) cacc[r2][j] = 0.f;
    #pragma unroll
    for (int g = 0; g < 2; ++g) {
      const int colbase = g * 128 + tc * 4;
      const int e = colbase >> 6, rbase = colbase & 63;
      const float* Crow = Cw + ((size_t)layer * NE + e) * RR * RR;
      for (int s4 = 0; s4 < 16; ++s4) {
        float4 v4[2];
        #pragma unroll
        for (int r2 = 0; r2 < 2; ++r2)
          v4[r2] = *reinterpret_cast<const float4*>(&sm.vbuf[tr * 2 + r2][e * 64 + s4 * 4]);
        #pragma unroll
        for (int j = 0; j < 4; ++j) {
          const float4 c4 = *reinterpret_cast<const float4*>(Crow + (size_t)(rbase + j) * RR + s4 * 4);
          #pragma unroll
          for (int r2 = 0; r2 < 2; ++r2)
            cacc[r2][g * 4 + j] += c4.x * v4[r2].x + c4.y * v4[r2].y +
                                   c4.z * v4[r2].z + c4.w * v4[r2].w;
        }
      }
    }

    // ---- w = gate*tanh(c): write directly as GEMM2 A-frags (hi/lo) ----
    #pragma unroll
    for (int g = 0; g < 2; ++g)
      #pragma unroll
      for (int r2 = 0; r2 < 2; ++r2) {
        const int row = tr * 2 + r2;
        const int rt = row >> 4;
        const int colb = g * 128 + tc * 4;             // k-dim of GEMM2
        const int ksl = colb >> 5, ii = colb & 7;
        const int lnf = (((colb >> 3) & 3) << 4) | (row & 15);
        const float gt = sm.gate[row][colb >> 6];
        u16 h[4], e4[4];
        #pragma unroll
        for (int j = 0; j < 4; ++j) {
          const float wval = gt * tanhf(cacc[r2][g * 4 + j]);
          h[j] = f2bf(wval); e4[j] = f2bf(wval - bf2f(h[j]));
        }
        uint2 hw, lw;
        hw.x = h[0] | (u32)h[1] << 16; hw.y = h[2] | (u32)h[3] << 16;
        lw.x = e4[0] | (u32)e4[1] << 16; lw.y = e4[2] | (u32)e4[3] << 16;
        *reinterpret_cast<uint2*>(&sm.u.Wf[rt][ksl][0][lnf][ii]) = hw;
        *reinterpret_cast<uint2*>(&sm.u.Wf[rt][ksl][1][lnf][ii]) = lw;
      }
    __syncthreads();

    // ---- GEMM2 + combine: ubar(32x1024) = w(32x256) @ U'(256x1024) ----
    for (int nc = 0; nc < 4; ++nc) {
      f32x4 a2[2][2];
      #pragma unroll
      for (int rt = 0; rt < 2; ++rt)
        #pragma unroll
        for (int c = 0; c < 2; ++c) a2[rt][c] = (f32x4){0.f, 0.f, 0.f, 0.f};
      for (int ks = 0; ks < 8; ++ks) {
        const bf16x8 ah0 = __builtin_bit_cast(bf16x8, *(const uint4*)&sm.u.Wf[0][ks][0][lane][0]);
        const bf16x8 al0 = __builtin_bit_cast(bf16x8, *(const uint4*)&sm.u.Wf[0][ks][1][lane][0]);
        const bf16x8 ah1 = __builtin_bit_cast(bf16x8, *(const uint4*)&sm.u.Wf[1][ks][0][lane][0]);
        const bf16x8 al1 = __builtin_bit_cast(bf16x8, *(const uint4*)&sm.u.Wf[1][ks][1][lane][0]);
        #pragma unroll
        for (int c = 0; c < 2; ++c) {
          const int ct = nc * 16 + wv * 2 + c;
          const u16* p = Ufl + ((((size_t)ct * 8 + ks) * 2) * 64 + lane) * 8;
          const bf16x8 bh = ld_frag_g(p);
          const bf16x8 bl = ld_frag_g(p + 512);
          a2[0][c] = MFMA16(ah0, bh, a2[0][c]);
          a2[0][c] = MFMA16(ah0, bl, a2[0][c]);
          a2[0][c] = MFMA16(al0, bh, a2[0][c]);
          a2[1][c] = MFMA16(ah1, bh, a2[1][c]);
          a2[1][c] = MFMA16(ah1, bl, a2[1][c]);
          a2[1][c] = MFMA16(al1, bh, a2[1][c]);
        }
      }
      __syncthreads();   // prev nc's vbuf IO reads done (and C-step reads, nc=0)
      #pragma unroll
      for (int rt = 0; rt < 2; ++rt)
        #pragma unroll
        for (int c = 0; c < 2; ++c)
          #pragma unroll
          for (int reg = 0; reg < 4; ++reg) {
            const int row = rt * 16 + lg * 4 + reg;
            const int col = (wv * 2 + c) * 16 + l15;
            sm.vbuf[row][col] = a2[rt][c][reg];
          }
      __syncthreads();
      // vectorized combine: out = x0*(ubar + bias) + x_l  (gates sum to 1)
      {
        const int row = t >> 4;            // 0..31
        const int c0 = (t & 15) * 4;       // 0..60
        #pragma unroll
        for (int j = 0; j < 4; ++j) {
          const int cl = j * 64 + c0;      // 0..255
          const int col = nc * 256 + cl;
          const float4 ub = *reinterpret_cast<const float4*>(&sm.vbuf[row][cl]);
          const float4 bv = *reinterpret_cast<const float4*>(bias + (size_t)layer * DIM + col);
          const size_t off = (size_t)(b0 + row) * DIM + col;
          const float4 x0v = *reinterpret_cast<const float4*>(x + off);
          const float4 xlv = *reinterpret_cast<const float4*>(xin + off);
          float4 o;
          o.x = x0v.x * (ub.x + bv.x) + xlv.x;
          o.y = x0v.y * (ub.y + bv.y) + xlv.y;
          o.z = x0v.z * (ub.z + bv.z) + xlv.z;
          o.w = x0v.w * (ub.w + bv.w) + xlv.w;
          *reinterpret_cast<float4*>(out + off) = o;
        }
      }
    }
  }
}

extern "C" void kernel_launch(void* const* d_in, const int* in_sizes, int n_in,
                              void* d_out, int out_size, void* d_ws, size_t ws_size,
                              hipStream_t stream) {
  const float* x    = (const float*)d_in[0];
  const float* Uw   = (const float*)d_in[1];
  const float* Vw   = (const float*)d_in[2];
  const float* Cw   = (const float*)d_in[3];
  const float* bias = (const float*)d_in[4];
  const float* G    = (const float*)d_in[5];
  float* out = (float*)d_out;
  u16* Vf = (u16*)d_ws;
  u16* Uf = Vf + VF_TOTAL;

  hipLaunchKernelGGL(convert_frags, dim3((NL * 16 * 32 * 64 + NL * 64 * 8 * 64) / 256),
                     dim3(256), 0, stream, Vw, Uw, Vf, Uf);

  const int B = in_sizes[0] / DIM;   // 16384
  hipLaunchKernelGGL(crossnet_mfma, dim3(B / TB), dim3(512), 0, stream,
                     x, Cw, bias, G, Vf, Uf, out);
}